// Round 1
// baseline (1574.542 us; speedup 1.0000x reference)
//
#include <hip/hip_runtime.h>

#define N_NODES 30000
#define N_EDGES 120000
#define IN_DIM  9
#define ED_DIM  3
#define H       32
#define G_GRAPHS 256

// ---------------------------------------------------------------- node embed
__global__ __launch_bounds__(256) void node_embed_k(
    const float* __restrict__ x, const float* __restrict__ Wn,
    const float* __restrict__ bn, float* __restrict__ s)
{
    int gid = blockIdx.x * 256 + threadIdx.x;
    if (gid >= N_NODES * H) return;
    int n = gid >> 5, o = gid & 31;
    float acc = bn[o];
    #pragma unroll
    for (int i = 0; i < IN_DIM; ++i)
        acc = fmaf(x[n * IN_DIM + i], Wn[i * H + o], acc);
    s[gid] = fmaxf(acc, 0.f);
}

// ---------------------------------------------------------------- root term
// agg[n,o] = bconv[o] + sum_i s[n,i] * Wroot[i,o]
__global__ __launch_bounds__(256) void root_k(
    const float* __restrict__ s, const float* __restrict__ Wroot,
    const float* __restrict__ bconv, float* __restrict__ agg)
{
    int gid = blockIdx.x * 256 + threadIdx.x;
    if (gid >= N_NODES * H) return;
    int n = gid >> 5, o = gid & 31;
    float acc = bconv[o];
    #pragma unroll
    for (int i = 0; i < H; ++i)
        acc = fmaf(s[n * H + i], Wroot[i * H + o], acc);
    agg[gid] = acc;
}

// ---------------------------------------------------------------- edge conv
// One thread handles one edge's HALF of the i-range (16 of 32 input dims).
// half is block-uniform (blockIdx parity) so Wnn addresses stay wave-uniform
// -> compiler can emit s_load for the 128B weight rows, shared by all lanes.
// msg[o] = sum_{j<32} ea[j] * sum_i h[i]*Wnn[j, i*32+o]  + sum_i h[i]*bnn[i*32+o]
__global__ __launch_bounds__(256) void edge_k(
    const float* __restrict__ s, const float* __restrict__ eattr,
    const int* __restrict__ ei, const float* __restrict__ We,
    const float* __restrict__ be, const float* __restrict__ Wnn,
    const float* __restrict__ bnn, float* __restrict__ agg)
{
    const int half = blockIdx.x & 1;
    const int e = (blockIdx.x >> 1) * 256 + threadIdx.x;
    if (e >= N_EDGES) return;
    const int i0 = half * 16;

    // edge embedding ea = relu(edge_attr @ We + be), recomputed (cheap: 96 FMA)
    const float a0 = eattr[e * 3 + 0];
    const float a1 = eattr[e * 3 + 1];
    const float a2 = eattr[e * 3 + 2];
    float ea[H];
    #pragma unroll
    for (int j = 0; j < H; ++j)
        ea[j] = fmaxf(fmaf(a2, We[2 * H + j],
                      fmaf(a1, We[H + j],
                      fmaf(a0, We[j], be[j]))), 0.f);

    const int srcn = ei[e];
    const int dstn = ei[N_EDGES + e];

    float h[16];
    const float4* hp = (const float4*)(s + srcn * H + i0);
    #pragma unroll
    for (int q = 0; q < 4; ++q) {
        float4 v = hp[q];
        h[4 * q + 0] = v.x; h[4 * q + 1] = v.y;
        h[4 * q + 2] = v.z; h[4 * q + 3] = v.w;
    }

    float acc[H];
    #pragma unroll
    for (int o = 0; o < H; ++o) acc[o] = 0.f;

    #pragma unroll 1
    for (int j = 0; j < H; ++j) {
        const float cj = ea[j];
        const float* wbase = Wnn + j * (H * H) + i0 * H;
        #pragma unroll 2
        for (int ii = 0; ii < 16; ++ii) {
            const float c = cj * h[ii];
            const float* w = wbase + ii * H;
            #pragma unroll
            for (int o = 0; o < H; ++o)
                acc[o] = fmaf(c, w[o], acc[o]);
        }
    }
    // bnn contribution: Wmat bias row, coefficient = h[i]
    {
        const float* wbase = bnn + i0 * H;
        #pragma unroll 2
        for (int ii = 0; ii < 16; ++ii) {
            const float c = h[ii];
            const float* w = wbase + ii * H;
            #pragma unroll
            for (int o = 0; o < H; ++o)
                acc[o] = fmaf(c, w[o], acc[o]);
        }
    }

    float* ag = agg + dstn * H;
    #pragma unroll
    for (int o = 0; o < H; ++o)
        atomicAdd(ag + o, acc[o]);
}

// ---------------------------------------------------------------- relu + res
__global__ __launch_bounds__(256) void finalize_k(
    const float* __restrict__ agg, float* __restrict__ s)
{
    int gid = blockIdx.x * 256 + threadIdx.x;
    if (gid >= N_NODES * H) return;
    s[gid] = fmaxf(agg[gid], 0.f) + s[gid];
}

// ---------------------------------------------------------------- pooling
__global__ __launch_bounds__(256) void pool_k(
    const float* __restrict__ s, const int* __restrict__ batch,
    float* __restrict__ pooled)
{
    int gid = blockIdx.x * 256 + threadIdx.x;
    if (gid >= N_NODES * H) return;
    int n = gid >> 5, o = gid & 31;
    atomicAdd(pooled + batch[n] * H + o, s[gid]);
}

// ---------------------------------------------------------------- MLP head
__global__ __launch_bounds__(128) void mlp_k(
    const float* __restrict__ pooled,
    const float* __restrict__ W1, const float* __restrict__ b1,
    const float* __restrict__ W2, const float* __restrict__ b2,
    const float* __restrict__ W3, const float* __restrict__ b3,
    float* __restrict__ out)
{
    __shared__ float p[H];
    __shared__ float h1[128];
    __shared__ float h2[64];
    const int g = blockIdx.x, t = threadIdx.x;
    if (t < H) p[t] = pooled[g * H + t];
    __syncthreads();
    float a = b1[t];
    #pragma unroll
    for (int i = 0; i < H; ++i)
        a = fmaf(p[i], W1[i * 128 + t], a);
    h1[t] = fmaxf(a, 0.f);
    __syncthreads();
    if (t < 64) {
        float a2 = b2[t];
        #pragma unroll 4
        for (int i = 0; i < 128; ++i)
            a2 = fmaf(h1[i], W2[i * 64 + t], a2);
        h2[t] = fmaxf(a2, 0.f);
    }
    __syncthreads();
    if (t < 64) {
        float v = h2[t] * W3[t];
        #pragma unroll
        for (int off = 32; off > 0; off >>= 1)
            v += __shfl_down(v, off);
        if (t == 0) out[g] = v + b3[0];
    }
}

// ---------------------------------------------------------------- launcher
extern "C" void kernel_launch(void* const* d_in, const int* in_sizes, int n_in,
                              void* d_out, int out_size, void* d_ws, size_t ws_size,
                              hipStream_t stream)
{
    const float* x     = (const float*)d_in[0];
    const int*   ei    = (const int*)  d_in[1];
    const float* eattr = (const float*)d_in[2];
    const int*   batch = (const int*)  d_in[3];
    const float* Wn    = (const float*)d_in[4];
    const float* bn    = (const float*)d_in[5];
    const float* We    = (const float*)d_in[6];
    const float* be    = (const float*)d_in[7];
    const float* Wnn   = (const float*)d_in[8];
    const float* bnn   = (const float*)d_in[9];
    const float* Wroot = (const float*)d_in[10];
    const float* bconv = (const float*)d_in[11];
    const float* W1    = (const float*)d_in[12];
    const float* b1    = (const float*)d_in[13];
    const float* W2    = (const float*)d_in[14];
    const float* b2    = (const float*)d_in[15];
    const float* W3    = (const float*)d_in[16];
    const float* b3    = (const float*)d_in[17];
    float* out = (float*)d_out;

    float* s      = (float*)d_ws;            // N*H
    float* agg    = s + N_NODES * H;         // N*H
    float* pooled = agg + N_NODES * H;       // G*H

    const dim3 blk(256);
    const int nw_grid = (N_NODES * H + 255) / 256;   // 3750
    const int e_grid  = ((N_EDGES + 255) / 256) * 2; // 938 (i-range split x2)

    node_embed_k<<<nw_grid, blk, 0, stream>>>(x, Wn, bn, s);

    for (int k = 0; k < 3; ++k) {
        root_k<<<nw_grid, blk, 0, stream>>>(s, Wroot + k * H * H,
                                            bconv + k * H, agg);
        edge_k<<<e_grid, blk, 0, stream>>>(s, eattr, ei, We, be,
                                           Wnn + k * H * H * H,
                                           bnn + k * H * H, agg);
        finalize_k<<<nw_grid, blk, 0, stream>>>(agg, s);
    }

    hipMemsetAsync(pooled, 0, G_GRAPHS * H * sizeof(float), stream);
    pool_k<<<nw_grid, blk, 0, stream>>>(s, batch, pooled);
    mlp_k<<<G_GRAPHS, 128, 0, stream>>>(pooled, W1, b1, W2, b2, W3, b3, out);
}

// Round 2
// 166.382 us; speedup vs baseline: 9.4634x; 9.4634x over previous
//
#include <hip/hip_runtime.h>
#include <hip/hip_bf16.h>

#define N_NODES 30000
#define N_EDGES 120000
#define IN_DIM  9
#define H       32
#define G_GRAPHS 256
#define NSTEP   66   // K = 33*32 = 1056, K-step 16

typedef __attribute__((ext_vector_type(8)))  short short8v;
typedef __attribute__((ext_vector_type(16))) float f32x16;

__device__ __forceinline__ unsigned short bfb(float x) {
    __hip_bfloat16 h = __float2bfloat16(x);
    return __builtin_bit_cast(unsigned short, h);
}

// ------------------------------------------------- weights -> bf16 frag order
// bfrag[k][step][lane][t] = Wf_k[step*16 + (lane>>5)*8 + t , lane&31]
// Wf_k = [Wnn_k (1024x32); bnn_k (32x32)]  (same flat layout as inputs)
__global__ __launch_bounds__(256) void wconv_k(
    const float* __restrict__ Wnn, const float* __restrict__ bnn,
    unsigned short* __restrict__ bfrag)
{
    int gid = blockIdx.x * 256 + threadIdx.x;
    if (gid >= 3 * NSTEP * 512) return;
    int layer = gid / (NSTEP * 512);
    int rem   = gid % (NSTEP * 512);
    int step  = rem >> 9;
    int lane  = (rem >> 3) & 63;
    int t     = gid & 7;
    int krow  = step * 16 + ((lane >> 5) << 3) + t;   // 0..1055
    int col   = lane & 31;
    float v = (krow < 1024) ? Wnn[layer * 32768 + krow * 32 + col]
                            : bnn[layer * 1024 + (krow - 1024) * 32 + col];
    bfrag[gid] = bfb(v);
}

// ---------------------------------------------------------------- node embed
__global__ __launch_bounds__(256) void node_embed_k(
    const float* __restrict__ x, const float* __restrict__ Wn,
    const float* __restrict__ bn, float* __restrict__ s)
{
    int gid = blockIdx.x * 256 + threadIdx.x;
    if (gid >= N_NODES * H) return;
    int n = gid >> 5, o = gid & 31;
    float acc = bn[o];
    #pragma unroll
    for (int i = 0; i < IN_DIM; ++i)
        acc = fmaf(x[n * IN_DIM + i], Wn[i * H + o], acc);
    s[gid] = fmaxf(acc, 0.f);
}

// ---------------------------------------------------------------- root term
__global__ __launch_bounds__(256) void root_k(
    const float* __restrict__ s, const float* __restrict__ Wroot,
    const float* __restrict__ bconv, float* __restrict__ agg)
{
    int gid = blockIdx.x * 256 + threadIdx.x;
    if (gid >= N_NODES * H) return;
    int n = gid >> 5, o = gid & 31;
    float acc = bconv[o];
    #pragma unroll
    for (int i = 0; i < H; ++i)
        acc = fmaf(s[n * H + i], Wroot[i * H + o], acc);
    agg[gid] = acc;
}

// ------------------------------------------------------------ edge conv MFMA
// Wave tile: 64 edges = 2 M-tiles of 32. msg = Z @ Wf via mfma_f32_32x32x16_bf16.
// A-frag (M-tile m, K-step s): row = lane&31 (edge), k = (lane>>5)*8 + t
//   -> z = ea[e, s>>1] * h[e, (s&1)*16 + (lane>>5)*8 + t]  (ea row 32 == 1 -> bnn)
// D-frag: col = lane&31 (=o), row = (reg&3) + 8*(reg>>2) + 4*(lane>>5)  [m74/m101]
__global__ __launch_bounds__(256) void edge_mfma_k(
    const float* __restrict__ s, const float* __restrict__ eattr,
    const int* __restrict__ ei, const float* __restrict__ We,
    const float* __restrict__ be, const unsigned short* __restrict__ bfrag,
    float* __restrict__ agg)
{
    const int wave = threadIdx.x >> 6;
    const int lane = threadIdx.x & 63;
    const int ebase = blockIdx.x * 256 + wave * 64;
    if (ebase >= N_EDGES) return;           // wave-granular tail (120000 % 64 == 0)
    const int er = lane & 31;
    const int hi = lane >> 5;

    const int e0 = ebase + er;
    const int e1 = ebase + 32 + er;

    const float a00 = eattr[e0 * 3 + 0], a01 = eattr[e0 * 3 + 1], a02 = eattr[e0 * 3 + 2];
    const float a10 = eattr[e1 * 3 + 0], a11 = eattr[e1 * 3 + 1], a12 = eattr[e1 * 3 + 2];

    const int src0 = ei[e0], src1 = ei[e1];

    // h[e, (q*16) + hi*8 + 0..7] for q=0,1  -> 16 floats per M-tile
    float h0[16], h1[16];
    {
        const float* r0 = s + src0 * H + hi * 8;
        const float* r1 = s + src1 * H + hi * 8;
        #pragma unroll
        for (int q = 0; q < 2; ++q) {
            float4 u0 = *(const float4*)(r0 + q * 16);
            float4 u1 = *(const float4*)(r0 + q * 16 + 4);
            float4 v0 = *(const float4*)(r1 + q * 16);
            float4 v1 = *(const float4*)(r1 + q * 16 + 4);
            h0[q*8+0]=u0.x; h0[q*8+1]=u0.y; h0[q*8+2]=u0.z; h0[q*8+3]=u0.w;
            h0[q*8+4]=u1.x; h0[q*8+5]=u1.y; h0[q*8+6]=u1.z; h0[q*8+7]=u1.w;
            h1[q*8+0]=v0.x; h1[q*8+1]=v0.y; h1[q*8+2]=v0.z; h1[q*8+3]=v0.w;
            h1[q*8+4]=v1.x; h1[q*8+5]=v1.y; h1[q*8+6]=v1.z; h1[q*8+7]=v1.w;
        }
    }

    f32x16 acc0 = {};
    f32x16 acc1 = {};
    float ea0 = 1.f, ea1 = 1.f;

    #pragma unroll
    for (int step = 0; step < NSTEP; ++step) {
        const int j = step >> 1;
        if ((step & 1) == 0) {
            if (j < 32) {
                const float w0 = We[j], w1 = We[32 + j], w2 = We[64 + j], bb = be[j];
                ea0 = fmaxf(fmaf(a02, w2, fmaf(a01, w1, fmaf(a00, w0, bb))), 0.f);
                ea1 = fmaxf(fmaf(a12, w2, fmaf(a11, w1, fmaf(a10, w0, bb))), 0.f);
            } else { ea0 = 1.f; ea1 = 1.f; }
        }
        short8v A0, A1;
        #pragma unroll
        for (int t = 0; t < 8; ++t) {
            A0[t] = (short)bfb(ea0 * h0[(step & 1) * 8 + t]);
            A1[t] = (short)bfb(ea1 * h1[(step & 1) * 8 + t]);
        }
        const short8v B = *(const short8v*)(bfrag + ((step * 64 + lane) << 3));
        acc0 = __builtin_amdgcn_mfma_f32_32x32x16_bf16(A0, B, acc0, 0, 0, 0);
        acc1 = __builtin_amdgcn_mfma_f32_32x32x16_bf16(A1, B, acc1, 0, 0, 0);
    }

    // scatter: one atomic per (edge, o)
    const int* dsts = ei + N_EDGES;
    const int o = lane & 31;
    #pragma unroll
    for (int reg = 0; reg < 16; ++reg) {
        const int r = (reg & 3) + 8 * (reg >> 2) + 4 * hi;
        const int d0 = dsts[ebase + r];
        const int d1 = dsts[ebase + 32 + r];
        atomicAdd(agg + d0 * H + o, acc0[reg]);
        atomicAdd(agg + d1 * H + o, acc1[reg]);
    }
}

// ---------------------------------------------------------------- relu + res
__global__ __launch_bounds__(256) void finalize_k(
    const float* __restrict__ agg, float* __restrict__ s)
{
    int gid = blockIdx.x * 256 + threadIdx.x;
    if (gid >= N_NODES * H) return;
    s[gid] = fmaxf(agg[gid], 0.f) + s[gid];
}

// ---------------------------------------------------------------- pooling
__global__ __launch_bounds__(256) void pool_k(
    const float* __restrict__ s, const int* __restrict__ batch,
    float* __restrict__ pooled)
{
    int gid = blockIdx.x * 256 + threadIdx.x;
    if (gid >= N_NODES * H) return;
    int n = gid >> 5, o = gid & 31;
    atomicAdd(pooled + batch[n] * H + o, s[gid]);
}

// ---------------------------------------------------------------- MLP head
__global__ __launch_bounds__(128) void mlp_k(
    const float* __restrict__ pooled,
    const float* __restrict__ W1, const float* __restrict__ b1,
    const float* __restrict__ W2, const float* __restrict__ b2,
    const float* __restrict__ W3, const float* __restrict__ b3,
    float* __restrict__ out)
{
    __shared__ float p[H];
    __shared__ float h1[128];
    __shared__ float h2[64];
    const int g = blockIdx.x, t = threadIdx.x;
    if (t < H) p[t] = pooled[g * H + t];
    __syncthreads();
    float a = b1[t];
    #pragma unroll
    for (int i = 0; i < H; ++i)
        a = fmaf(p[i], W1[i * 128 + t], a);
    h1[t] = fmaxf(a, 0.f);
    __syncthreads();
    if (t < 64) {
        float a2 = b2[t];
        #pragma unroll 4
        for (int i = 0; i < 128; ++i)
            a2 = fmaf(h1[i], W2[i * 64 + t], a2);
        h2[t] = fmaxf(a2, 0.f);
    }
    __syncthreads();
    if (t < 64) {
        float v = h2[t] * W3[t];
        #pragma unroll
        for (int off = 32; off > 0; off >>= 1)
            v += __shfl_down(v, off);
        if (t == 0) out[g] = v + b3[0];
    }
}

// ---------------------------------------------------------------- launcher
extern "C" void kernel_launch(void* const* d_in, const int* in_sizes, int n_in,
                              void* d_out, int out_size, void* d_ws, size_t ws_size,
                              hipStream_t stream)
{
    const float* x     = (const float*)d_in[0];
    const int*   ei    = (const int*)  d_in[1];
    const float* eattr = (const float*)d_in[2];
    const int*   batch = (const int*)  d_in[3];
    const float* Wn    = (const float*)d_in[4];
    const float* bn    = (const float*)d_in[5];
    const float* We    = (const float*)d_in[6];
    const float* be    = (const float*)d_in[7];
    const float* Wnn   = (const float*)d_in[8];
    const float* bnn   = (const float*)d_in[9];
    const float* Wroot = (const float*)d_in[10];
    const float* bconv = (const float*)d_in[11];
    const float* W1    = (const float*)d_in[12];
    const float* b1    = (const float*)d_in[13];
    const float* W2    = (const float*)d_in[14];
    const float* b2    = (const float*)d_in[15];
    const float* W3    = (const float*)d_in[16];
    const float* b3    = (const float*)d_in[17];
    float* out = (float*)d_out;

    float* s      = (float*)d_ws;                    // N*H
    float* agg    = s + N_NODES * H;                 // N*H
    float* pooled = agg + N_NODES * H;               // G*H
    unsigned short* bfrag = (unsigned short*)(pooled + G_GRAPHS * H); // 3*66*512

    const dim3 blk(256);
    const int nw_grid = (N_NODES * H + 255) / 256;   // 3750
    const int e_grid  = (N_EDGES + 255) / 256;       // 469 (256 edges/block)
    const int w_grid  = (3 * NSTEP * 512 + 255) / 256;

    wconv_k<<<w_grid, blk, 0, stream>>>(Wnn, bnn, bfrag);
    node_embed_k<<<nw_grid, blk, 0, stream>>>(x, Wn, bn, s);

    for (int k = 0; k < 3; ++k) {
        root_k<<<nw_grid, blk, 0, stream>>>(s, Wroot + k * H * H,
                                            bconv + k * H, agg);
        edge_mfma_k<<<e_grid, blk, 0, stream>>>(s, eattr, ei, We, be,
                                                bfrag + k * NSTEP * 512, agg);
        finalize_k<<<nw_grid, blk, 0, stream>>>(agg, s);
    }

    hipMemsetAsync(pooled, 0, G_GRAPHS * H * sizeof(float), stream);
    pool_k<<<nw_grid, blk, 0, stream>>>(s, batch, pooled);
    mlp_k<<<G_GRAPHS, 128, 0, stream>>>(pooled, W1, b1, W2, b2, W3, b3, out);
}